// Round 4
// baseline (602.878 us; speedup 1.0000x reference)
//
#include <hip/hip_runtime.h>

#define NN 100000
#define NE 6400000
#define NEG_SLOPE 0.2f
#define SLICE 10240            // nodes per LDS slice (122880 B LDS)
#define NSLICE 10              // NSLICE*SLICE = 102400 >= NN

// ---------------- node pass: pack={h0,h1,a_src,a_dst}, plus scalar tables ---
__global__ void gat_node(const float* __restrict__ x, const float* __restrict__ W,
                         const float* __restrict__ att_src, const float* __restrict__ att_dst,
                         float4* __restrict__ pack, float* __restrict__ asrc,
                         float* __restrict__ adst, int n) {
    int gtid = blockIdx.x * blockDim.x + threadIdx.x;
    int wave = gtid >> 6, lane = threadIdx.x & 63;
    int nw = (gridDim.x * blockDim.x) >> 6;
    float as0 = att_src[0], as1 = att_src[1];
    float ad0 = att_dst[0], ad1 = att_dst[1];
    for (int node = wave; node < n; node += nw) {
        float2 xx = *(const float2*)(x + (size_t)node * 128 + lane * 2);
        float2 w0 = *(const float2*)(W + lane * 4);
        float2 w1 = *(const float2*)(W + lane * 4 + 2);
        float c0 = xx.x * w0.x + xx.y * w1.x;
        float c1 = xx.x * w0.y + xx.y * w1.y;
        #pragma unroll
        for (int off = 32; off; off >>= 1) {
            c0 += __shfl_down(c0, off);
            c1 += __shfl_down(c1, off);
        }
        if (lane == 0) {
            float s = c0 * as0 + c1 * as1;
            float d = c0 * ad0 + c1 * ad1;
            pack[node] = make_float4(c0, c1, s, d);
            asrc[node] = s;
            adst[node] = d;
        }
    }
}

// ---------------- slice scan: hoisted unconditional gathers ----------------
// block = (slice s, chunk c). All gathers issued unconditionally (indices are
// always valid node ids) so the compiler pipelines 16 loads per 8 edges with
// a single wait; only the LDS atomics are predicated.
__global__ __launch_bounds__(1024) void
gat_scan(const int* __restrict__ src, const int* __restrict__ dst,
         const float* __restrict__ ea, const float4* __restrict__ pack,
         const float* __restrict__ adst,
         const float* __restrict__ W_edge, const float* __restrict__ att_edge,
         float* __restrict__ partial, int nchunk, int chunk) {
    __shared__ float sacc[SLICE * 3];
    const int s = blockIdx.x / nchunk;
    const int c = blockIdx.x % nchunk;
    const int lo = s * SLICE;

    for (int j = threadIdx.x; j < SLICE * 3; j += 1024) sacc[j] = 0.0f;
    __syncthreads();

    const float k = W_edge[0] * att_edge[0] + W_edge[1] * att_edge[1];
    const int base = c * chunk;

    for (int o = threadIdx.x * 8; o < chunk; o += 1024 * 8) {
        const int i = base + o;
        int4   da = *(const int4*)(dst + i), db = *(const int4*)(dst + i + 4);
        int4   sa = *(const int4*)(src + i), sb = *(const int4*)(src + i + 4);
        float4 e0 = *(const float4*)(ea + i), e1 = *(const float4*)(ea + i + 4);
        int   dd[8] = {da.x, da.y, da.z, da.w, db.x, db.y, db.z, db.w};
        int   ss[8] = {sa.x, sa.y, sa.z, sa.w, sb.x, sb.y, sb.z, sb.w};
        float ee[8] = {e0.x, e0.y, e0.z, e0.w, e1.x, e1.y, e1.z, e1.w};
        float4 ps[8];
        float  ad[8];
        #pragma unroll
        for (int u = 0; u < 8; ++u) {       // load-only stage: 16 independent gathers
            ps[u] = pack[ss[u]];
            ad[u] = adst[dd[u]];
        }
        #pragma unroll
        for (int u = 0; u < 8; ++u) {       // compute + masked LDS accumulate
            unsigned off = (unsigned)(dd[u] - lo);
            float al = ps[u].z + ad[u] + k * ee[u];
            al = al > 0.0f ? al : NEG_SLOPE * al;
            float ex = __expf(al);
            if (off < SLICE) {
                atomicAdd(&sacc[off * 3],     ex);
                atomicAdd(&sacc[off * 3 + 1], ex * ps[u].x);
                atomicAdd(&sacc[off * 3 + 2], ex * ps[u].y);
            }
        }
    }
    __syncthreads();

    float* pout = partial + (size_t)blockIdx.x * (SLICE * 3);
    for (int j = threadIdx.x; j < SLICE * 3; j += 1024) pout[j] = sacc[j];
}

// ---------------- combine partials: out = num/denom + bias, invd -----------
__global__ void gat_combine(const float* __restrict__ partial,
                            const float* __restrict__ bias,
                            float* __restrict__ out, float* __restrict__ invd,
                            int nchunk) {
    int n = blockIdx.x * blockDim.x + threadIdx.x;
    if (n >= NN) return;
    int sl = n / SLICE, off = n % SLICE;
    const float* p = partial + (size_t)sl * nchunk * (SLICE * 3) + (size_t)off * 3;
    float de = 0.f, n0 = 0.f, n1 = 0.f;
    for (int c = 0; c < nchunk; ++c, p += SLICE * 3) {
        de += p[0]; n0 += p[1]; n1 += p[2];
    }
    float inv = 1.0f / (de + 1e-16f);
    out[2 * n]     = n0 * inv + bias[0];
    out[2 * n + 1] = n1 * inv + bias[1];
    invd[n] = inv;
}

// ---------------- alpha pass: recompute ex, alpha = ex * invd[dst] ---------
__global__ void gat_alpha(const int* __restrict__ src, const int* __restrict__ dst,
                          const float* __restrict__ ea,
                          const float* __restrict__ asrc, const float* __restrict__ adst,
                          const float* __restrict__ W_edge, const float* __restrict__ att_edge,
                          const float* __restrict__ invd, float* __restrict__ alpha) {
    const float k = W_edge[0] * att_edge[0] + W_edge[1] * att_edge[1];
    int i = (blockIdx.x * blockDim.x + threadIdx.x) * 4;
    if (i >= NE) return;
    int4   d4 = *(const int4*)(dst + i);
    int4   s4 = *(const int4*)(src + i);
    float4 e4 = *(const float4*)(ea + i);
    const int*   dp = (const int*)&d4;
    const int*   sp = (const int*)&s4;
    const float* ep = (const float*)&e4;
    float as[4], ad[4], iv[4];
    #pragma unroll
    for (int u = 0; u < 4; ++u) {           // load-only stage
        as[u] = asrc[sp[u]];
        ad[u] = adst[dp[u]];
        iv[u] = invd[dp[u]];
    }
    float4 a;
    float* ap = (float*)&a;
    #pragma unroll
    for (int u = 0; u < 4; ++u) {
        float al = as[u] + ad[u] + k * ep[u];
        al = al > 0.0f ? al : NEG_SLOPE * al;
        ap[u] = __expf(al) * iv[u];
    }
    *(float4*)(alpha + i) = a;
}

extern "C" void kernel_launch(void* const* d_in, const int* in_sizes, int n_in,
                              void* d_out, int out_size, void* d_ws, size_t ws_size,
                              hipStream_t stream) {
    const float* x        = (const float*)d_in[0];
    const int*   ei       = (const int*)  d_in[1];
    const float* ea       = (const float*)d_in[2];
    const float* W_src    = (const float*)d_in[3];
    const float* W_edge   = (const float*)d_in[4];
    const float* att_src  = (const float*)d_in[5];
    const float* att_dst  = (const float*)d_in[6];
    const float* att_edge = (const float*)d_in[7];
    const float* bias     = (const float*)d_in[8];

    float* out   = (float*)d_out;      // [N,2]
    float* alpha = out + 2 * NN;       // [E]

    // ws fixed region: pack [NN float4] | asrc | adst | invd
    float4* pack = (float4*)d_ws;
    float*  asrc = (float*)(pack + NN);
    float*  adst = asrc + NN;
    float*  invd = adst + NN;
    size_t fixed_bytes = (size_t)NN * 16 + 3 * (size_t)NN * 4;

    // choose chunk count: 25 (250 blocks, partial in ws) if ws fits, else
    // 20 (200 blocks, partial in the alpha region of d_out)
    int nchunk;
    float* partial;
    size_t partial25 = (size_t)NSLICE * 25 * SLICE * 3 * 4;
    if (ws_size >= fixed_bytes + partial25) {
        nchunk = 25;
        partial = invd + NN;
    } else {
        nchunk = 20;
        partial = alpha;           // 200*30720 = 6.144M floats <= 6.4M
    }
    const int chunk = NE / nchunk; // 256000 or 320000, both divisible by 8

    const int* src = ei;
    const int* dst = ei + NE;

    gat_node   <<<1024, 256, 0, stream>>>(x, W_src, att_src, att_dst, pack, asrc, adst, NN);
    gat_scan   <<<NSLICE * nchunk, 1024, 0, stream>>>(src, dst, ea, pack, adst,
                                                      W_edge, att_edge, partial, nchunk, chunk);
    gat_combine<<<(NN + 255) / 256, 256, 0, stream>>>(partial, bias, out, invd, nchunk);
    gat_alpha  <<<NE / (256 * 4), 256, 0, stream>>>(src, dst, ea, asrc, adst,
                                                    W_edge, att_edge, invd, alpha);
}

// Round 5
// 248.474 us; speedup vs baseline: 2.4263x; 2.4263x over previous
//
#include <hip/hip_runtime.h>

#define NN 100000
#define NE 6400000
#define NEG_SLOPE 0.2f
#define SLICE 10240            // nodes per LDS slice (122880 B LDS)
#define NSLICE 10              // NSLICE*SLICE = 102400 >= NN

// ---------------- node pass: pack={h0,h1,a_src,a_dst}, plus scalar tables ---
__global__ void gat_node(const float* __restrict__ x, const float* __restrict__ W,
                         const float* __restrict__ att_src, const float* __restrict__ att_dst,
                         float4* __restrict__ pack, float* __restrict__ asrc,
                         float* __restrict__ adst, int n) {
    int gtid = blockIdx.x * blockDim.x + threadIdx.x;
    int wave = gtid >> 6, lane = threadIdx.x & 63;
    int nw = (gridDim.x * blockDim.x) >> 6;
    float as0 = att_src[0], as1 = att_src[1];
    float ad0 = att_dst[0], ad1 = att_dst[1];
    for (int node = wave; node < n; node += nw) {
        float2 xx = *(const float2*)(x + (size_t)node * 128 + lane * 2);
        float2 w0 = *(const float2*)(W + lane * 4);
        float2 w1 = *(const float2*)(W + lane * 4 + 2);
        float c0 = xx.x * w0.x + xx.y * w1.x;
        float c1 = xx.x * w0.y + xx.y * w1.y;
        #pragma unroll
        for (int off = 32; off; off >>= 1) {
            c0 += __shfl_down(c0, off);
            c1 += __shfl_down(c1, off);
        }
        if (lane == 0) {
            float s = c0 * as0 + c1 * as1;
            float d = c0 * ad0 + c1 * ad1;
            pack[node] = make_float4(c0, c1, s, d);
            asrc[node] = s;
            adst[node] = d;
        }
    }
}

// ---------------- slice scan: clamped unconditional gathers ----------------
// Loads are issued unconditionally (compiler batches 16 gathers / 8 edges
// under one waitcnt), but rejected edges gather from a CLAMPED shared address
// (pack[0], adst[lo]) so all inactive lanes of a wave hit one broadcast line
// -> gather line-traffic stays at the accepted-edge level (~1/NSLICE).
__global__ __launch_bounds__(1024) void
gat_scan(const int* __restrict__ src, const int* __restrict__ dst,
         const float* __restrict__ ea, const float4* __restrict__ pack,
         const float* __restrict__ adst,
         const float* __restrict__ W_edge, const float* __restrict__ att_edge,
         float* __restrict__ partial, int nchunk, int chunk) {
    __shared__ float sacc[SLICE * 3];
    const int s = blockIdx.x / nchunk;
    const int c = blockIdx.x % nchunk;
    const int lo = s * SLICE;

    for (int j = threadIdx.x; j < SLICE * 3; j += 1024) sacc[j] = 0.0f;
    __syncthreads();

    const float k = W_edge[0] * att_edge[0] + W_edge[1] * att_edge[1];
    const int base = c * chunk;

    for (int o = threadIdx.x * 8; o < chunk; o += 1024 * 8) {
        const int i = base + o;
        int4   da = *(const int4*)(dst + i), db = *(const int4*)(dst + i + 4);
        int4   sa = *(const int4*)(src + i), sb = *(const int4*)(src + i + 4);
        float4 e0 = *(const float4*)(ea + i), e1 = *(const float4*)(ea + i + 4);
        int   dd[8] = {da.x, da.y, da.z, da.w, db.x, db.y, db.z, db.w};
        int   ss[8] = {sa.x, sa.y, sa.z, sa.w, sb.x, sb.y, sb.z, sb.w};
        float ee[8] = {e0.x, e0.y, e0.z, e0.w, e1.x, e1.y, e1.z, e1.w};
        unsigned off[8];
        float4 ps[8];
        float  ad[8];
        #pragma unroll
        for (int u = 0; u < 8; ++u) {       // unconditional issue, clamped address
            off[u] = (unsigned)(dd[u] - lo);
            bool acc = off[u] < SLICE;
            ps[u] = pack[acc ? ss[u] : 0];
            ad[u] = adst[acc ? dd[u] : lo];
        }
        #pragma unroll
        for (int u = 0; u < 8; ++u) {       // compute unconditional, LDS masked
            float al = ps[u].z + ad[u] + k * ee[u];
            al = al > 0.0f ? al : NEG_SLOPE * al;
            float ex = __expf(al);
            if (off[u] < SLICE) {
                atomicAdd(&sacc[off[u] * 3],     ex);
                atomicAdd(&sacc[off[u] * 3 + 1], ex * ps[u].x);
                atomicAdd(&sacc[off[u] * 3 + 2], ex * ps[u].y);
            }
        }
    }
    __syncthreads();

    float* pout = partial + (size_t)blockIdx.x * (SLICE * 3);
    for (int j = threadIdx.x; j < SLICE * 3; j += 1024) pout[j] = sacc[j];
}

// ---------------- combine partials: out = num/denom + bias, invd -----------
__global__ void gat_combine(const float* __restrict__ partial,
                            const float* __restrict__ bias,
                            float* __restrict__ out, float* __restrict__ invd,
                            int nchunk) {
    int n = blockIdx.x * blockDim.x + threadIdx.x;
    if (n >= NN) return;
    int sl = n / SLICE, off = n % SLICE;
    const float* p = partial + (size_t)sl * nchunk * (SLICE * 3) + (size_t)off * 3;
    float de = 0.f, n0 = 0.f, n1 = 0.f;
    for (int c = 0; c < nchunk; ++c, p += SLICE * 3) {
        de += p[0]; n0 += p[1]; n1 += p[2];
    }
    float inv = 1.0f / (de + 1e-16f);
    out[2 * n]     = n0 * inv + bias[0];
    out[2 * n + 1] = n1 * inv + bias[1];
    invd[n] = inv;
}

// ---------------- alpha pass: recompute ex, alpha = ex * invd[dst] ---------
__global__ void gat_alpha(const int* __restrict__ src, const int* __restrict__ dst,
                          const float* __restrict__ ea,
                          const float* __restrict__ asrc, const float* __restrict__ adst,
                          const float* __restrict__ W_edge, const float* __restrict__ att_edge,
                          const float* __restrict__ invd, float* __restrict__ alpha) {
    const float k = W_edge[0] * att_edge[0] + W_edge[1] * att_edge[1];
    int i = (blockIdx.x * blockDim.x + threadIdx.x) * 4;
    if (i >= NE) return;
    int4   d4 = *(const int4*)(dst + i);
    int4   s4 = *(const int4*)(src + i);
    float4 e4 = *(const float4*)(ea + i);
    const int*   dp = (const int*)&d4;
    const int*   sp = (const int*)&s4;
    const float* ep = (const float*)&e4;
    float as[4], ad[4], iv[4];
    #pragma unroll
    for (int u = 0; u < 4; ++u) {           // load-only stage
        as[u] = asrc[sp[u]];
        ad[u] = adst[dp[u]];
        iv[u] = invd[dp[u]];
    }
    float4 a;
    float* ap = (float*)&a;
    #pragma unroll
    for (int u = 0; u < 4; ++u) {
        float al = as[u] + ad[u] + k * ep[u];
        al = al > 0.0f ? al : NEG_SLOPE * al;
        ap[u] = __expf(al) * iv[u];
    }
    *(float4*)(alpha + i) = a;
}

extern "C" void kernel_launch(void* const* d_in, const int* in_sizes, int n_in,
                              void* d_out, int out_size, void* d_ws, size_t ws_size,
                              hipStream_t stream) {
    const float* x        = (const float*)d_in[0];
    const int*   ei       = (const int*)  d_in[1];
    const float* ea       = (const float*)d_in[2];
    const float* W_src    = (const float*)d_in[3];
    const float* W_edge   = (const float*)d_in[4];
    const float* att_src  = (const float*)d_in[5];
    const float* att_dst  = (const float*)d_in[6];
    const float* att_edge = (const float*)d_in[7];
    const float* bias     = (const float*)d_in[8];

    float* out   = (float*)d_out;      // [N,2]
    float* alpha = out + 2 * NN;       // [E]

    // ws fixed region: pack [NN float4] | asrc | adst | invd
    float4* pack = (float4*)d_ws;
    float*  asrc = (float*)(pack + NN);
    float*  adst = asrc + NN;
    float*  invd = adst + NN;
    size_t fixed_bytes = (size_t)NN * 16 + 3 * (size_t)NN * 4;

    // chunk count: 25 (250 blocks, partial in ws) if ws fits, else 20
    int nchunk;
    float* partial;
    size_t partial25 = (size_t)NSLICE * 25 * SLICE * 3 * 4;
    if (ws_size >= fixed_bytes + partial25) {
        nchunk = 25;
        partial = invd + NN;
    } else {
        nchunk = 20;
        partial = alpha;           // 200*30720 = 6.144M floats <= 6.4M
    }
    const int chunk = NE / nchunk;

    const int* src = ei;
    const int* dst = ei + NE;

    gat_node   <<<1024, 256, 0, stream>>>(x, W_src, att_src, att_dst, pack, asrc, adst, NN);
    gat_scan   <<<NSLICE * nchunk, 1024, 0, stream>>>(src, dst, ea, pack, adst,
                                                      W_edge, att_edge, partial, nchunk, chunk);
    gat_combine<<<(NN + 255) / 256, 256, 0, stream>>>(partial, bias, out, invd, nchunk);
    gat_alpha  <<<NE / (256 * 4), 256, 0, stream>>>(src, dst, ea, asrc, adst,
                                                    W_edge, att_edge, invd, alpha);
}